// Round 9
// baseline (180.674 us; speedup 1.0000x reference)
//
#include <hip/hip_runtime.h>
#include <math.h>

#define N_TOK 2048

typedef __attribute__((ext_vector_type(8))) short short8;   // 8 bf16
typedef __attribute__((ext_vector_type(4))) float f32x4;

__device__ __forceinline__ float gelu_f(float v) {
    return 0.5f * v * (1.0f + erff(v * 0.7071067811865475f));
}
__device__ __forceinline__ ushort f2bf(float x) {
    uint u = __float_as_uint(x);
    uint r = u + 0x7FFFu + ((u >> 16) & 1u);
    return (ushort)(r >> 16);
}
__device__ __forceinline__ float bf2f(ushort u) {
    return __uint_as_float((uint)u << 16);
}
// async global->LDS, 16B per lane; LDS dest = wave-uniform base + lane*16
__device__ __forceinline__ void gload16(const void* g, void* s) {
    __builtin_amdgcn_global_load_lds((const __attribute__((address_space(1))) void*)g,
                                     (__attribute__((address_space(3))) void*)s, 16, 0, 0);
}

// ---- prep: weight f32->bf16 convert (blocks 0..1279) + x transpose (1280..2303) ----
__global__ __launch_bounds__(256)
void prep(const float* __restrict__ w0, ushort* __restrict__ o0,
          const float* __restrict__ w1, ushort* __restrict__ o1,
          const float* __restrict__ w2, ushort* __restrict__ o2,
          const float* __restrict__ x, ushort* __restrict__ xt)
{
    __shared__ ushort sT[64 * 68];
    const int tid = threadIdx.x;
    int bx = blockIdx.x;
    if (bx < 1280) {
        int i4 = bx * 256 + tid;   // 327680 float4s total
        const float* src; ushort* dst; int idx;
        if (i4 < 196608)      { src = w0; dst = o0; idx = i4; }
        else if (i4 < 262144) { src = w1; dst = o1; idx = i4 - 196608; }
        else                  { src = w2; dst = o2; idx = i4 - 262144; }
        float4 v = *(const float4*)&src[idx * 4];
        ushort4 p; p.x = f2bf(v.x); p.y = f2bf(v.y); p.z = f2bf(v.z); p.w = f2bf(v.w);
        *(ushort4*)&dst[idx * 4] = p;
        return;
    }
    bx -= 1280;                                 // 1024 transpose blocks
    const int tok0 = (bx & 31) * 64;
    const int ch0 = ((bx >> 5) & 7) * 64;
    const int bi = bx >> 8;
    #pragma unroll
    for (int i = 0; i < 4; i++) {
        int ch = (tid >> 4) + i * 16;
        int t4 = (tid & 15) * 4;
        float4 v = *(const float4*)&x[((size_t)bi * 512 + ch0 + ch) * N_TOK + tok0 + t4];
        ushort4 p; p.x = f2bf(v.x); p.y = f2bf(v.y); p.z = f2bf(v.z); p.w = f2bf(v.w);
        *(ushort4*)&sT[ch * 68 + t4] = p;
    }
    __syncthreads();
    const int tr = (tid & 15) + (tid >> 6) * 16;
    const int cb = ((tid >> 4) & 3) * 16;
    uint vv[8];
    #pragma unroll
    for (int j = 0; j < 8; j++) {
        uint lo = sT[(cb + 2 * j) * 68 + tr];
        uint hi = sT[(cb + 2 * j + 1) * 68 + tr];
        vv[j] = lo | (hi << 16);
    }
    size_t base = ((size_t)bi * N_TOK + tok0 + tr) * 512 + ch0 + cb;
    *(uint4*)&xt[base]     = *(uint4*)&vv[0];
    *(uint4*)&xt[base + 8] = *(uint4*)&vv[4];
}

// ---- bf16 MFMA GEMM: C[b] = A @ Bt[b]^T (structure unchanged) ----
template<int MODE, int BM, int BN>
__global__ __launch_bounds__(256)
void bgemm(const ushort* __restrict__ A, const ushort* __restrict__ Bt, int M,
           ushort* __restrict__ qt, ushort* __restrict__ vc,
           float* __restrict__ outF, ushort* __restrict__ outB,
           const float* __restrict__ bias,
           const float* __restrict__ g, const float* __restrict__ be,
           const float* __restrict__ mu, const float* __restrict__ va,
           const ushort* __restrict__ residB)
{
    constexpr int MF = BM / 32, NF = BN / 32;
    __shared__ ushort sA[BM * 64];
    __shared__ ushort sB[BN * 64];
    const int tid = threadIdx.x;
    const int w = tid >> 6, l = tid & 63;
    const int l16 = l & 15, lg = l >> 4;
    const int wr = w >> 1, wc = w & 1;
    const int bi = blockIdx.z;
    const int m0 = blockIdx.y * BM, n0 = blockIdx.x * BN;
    const ushort* Bb = Bt + (size_t)bi * N_TOK * 512;
    const int srow = l >> 3, spos = l & 7;

    f32x4 acc[MF][NF];
    #pragma unroll
    for (int i = 0; i < MF; i++)
        #pragma unroll
        for (int j = 0; j < NF; j++) acc[i][j] = (f32x4){0.f, 0.f, 0.f, 0.f};

    for (int kt = 0; kt < 512; kt += 64) {
        __syncthreads();
        #pragma unroll
        for (int i = 0; i < BM / 32; i++) {
            int row = w * (BM / 4) + i * 8 + srow;
            int c = spos ^ (row & 7);
            gload16(A + (size_t)(m0 + row) * 512 + kt + c * 8,
                    sA + (w * (BM / 4) + i * 8) * 64);
        }
        #pragma unroll
        for (int i = 0; i < BN / 32; i++) {
            int row = w * (BN / 4) + i * 8 + srow;
            int c = spos ^ (row & 7);
            gload16(Bb + (size_t)(n0 + row) * 512 + kt + c * 8,
                    sB + (w * (BN / 4) + i * 8) * 64);
        }
        __syncthreads();
        #pragma unroll
        for (int ks = 0; ks < 2; ks++) {
            short8 af[MF], bfv[NF];
            #pragma unroll
            for (int mi = 0; mi < MF; mi++) {
                int row = wr * (BM / 2) + mi * 16 + l16;
                af[mi] = *(const short8*)&sA[row * 64 + (((ks * 4 + lg) ^ (row & 7)) << 3)];
            }
            #pragma unroll
            for (int ni = 0; ni < NF; ni++) {
                int row = wc * (BN / 2) + ni * 16 + l16;
                bfv[ni] = *(const short8*)&sB[row * 64 + (((ks * 4 + lg) ^ (row & 7)) << 3)];
            }
            __builtin_amdgcn_s_setprio(1);
            #pragma unroll
            for (int mi = 0; mi < MF; mi++)
                #pragma unroll
                for (int ni = 0; ni < NF; ni++)
                    acc[mi][ni] = __builtin_amdgcn_mfma_f32_16x16x32_bf16(
                        af[mi], bfv[ni], acc[mi][ni], 0, 0, 0);
            __builtin_amdgcn_s_setprio(0);
        }
    }

    const int chb = m0 + wr * (BM / 2);
    const int tkb = n0 + wc * (BN / 2);
    if (MODE == 0) {
        if (m0 < 1024) {
            // Q gets 0.125 * log2(e) so attention can use exp2 directly
            const float qs = (m0 < 512) ? 0.18033688f : 1.0f;
            #pragma unroll
            for (int mi = 0; mi < MF; mi++) {
                int ob = chb + mi * 16 + lg * 4;
                #pragma unroll
                for (int ni = 0; ni < NF; ni++) {
                    int tok = tkb + ni * 16 + l16;
                    ushort4 p;
                    p.x = f2bf(acc[mi][ni][0] * qs); p.y = f2bf(acc[mi][ni][1] * qs);
                    p.z = f2bf(acc[mi][ni][2] * qs); p.w = f2bf(acc[mi][ni][3] * qs);
                    *(ushort4*)&qt[((size_t)bi * N_TOK + tok) * 1024 + ob] = p;
                }
            }
        } else {
            #pragma unroll
            for (int mi = 0; mi < MF; mi++)
                #pragma unroll
                for (int r = 0; r < 4; r++) {
                    int o = chb + mi * 16 + lg * 4 + r - 1024;
                    #pragma unroll
                    for (int ni = 0; ni < NF; ni++) {
                        int tok = tkb + ni * 16 + l16;
                        vc[((size_t)bi * 512 + o) * N_TOK + tok] = f2bf(acc[mi][ni][r]);
                    }
                }
        }
    } else {
        #pragma unroll
        for (int mi = 0; mi < MF; mi++) {
            float inv[4], sh[4], bb[4];
            #pragma unroll
            for (int r = 0; r < 4; r++) {
                int o = chb + mi * 16 + lg * 4 + r;
                inv[r] = g[o] * rsqrtf(va[o] + 1e-5f);
                sh[r]  = be[o] - mu[o] * inv[r];
                bb[r]  = (MODE == 1) ? bias[o] : 0.f;
            }
            #pragma unroll
            for (int ni = 0; ni < NF; ni++) {
                int tok = tkb + ni * 16 + l16;
                ushort4 rv = *(const ushort4*)&residB[((size_t)bi * N_TOK + tok) * 512 +
                                                      chb + mi * 16 + lg * 4];
                float rr_[4] = {bf2f(rv.x), bf2f(rv.y), bf2f(rv.z), bf2f(rv.w)};
                float ov[4];
                #pragma unroll
                for (int r = 0; r < 4; r++) {
                    float y = (acc[mi][ni][r] + bb[r]) * inv[r] + sh[r];
                    ov[r] = gelu_f((MODE == 1) ? (y + rr_[r]) : (rr_[r] + y));
                }
                if (MODE == 1) {
                    ushort4 p;
                    p.x = f2bf(ov[0]); p.y = f2bf(ov[1]);
                    p.z = f2bf(ov[2]); p.w = f2bf(ov[3]);
                    *(ushort4*)&outB[((size_t)bi * N_TOK + tok) * 512 +
                                     chb + mi * 16 + lg * 4] = p;
                } else {
                    #pragma unroll
                    for (int r = 0; r < 4; r++) {
                        int o = chb + mi * 16 + lg * 4 + r;
                        outF[((size_t)bi * 512 + o) * N_TOK + tok] = ov[r];
                    }
                }
            }
        }
    }
}

// ---- MFMA flash attention: barrier-free, K/V direct from L2 ----
// qt: bf16 [b][2048][1024] (Q pre-scaled by 0.125*log2e ch 0..511, K ch 512..1023)
// vc: bf16 [b][512][2048]; aout: bf16 [b][2048][512]
// 4 waves/block (independent), 32 q-rows/wave; KV tile = 64.
// No __syncthreads anywhere: K/V fragments are per-lane 16B contiguous global
// loads (L2-resident via XCD clustering, L1-shared across the block's waves).
// Only LDS use: per-wave P round-trip (in-wave lgkmcnt ordering).
__global__ __launch_bounds__(256)
void attn_mfma(const ushort* __restrict__ qt, const ushort* __restrict__ vc,
               ushort* __restrict__ aout)
{
    __shared__ uint sPu[4][1024];       // per-wave P: 2 Mt x [16 q][32 u32], swizzled
    const int tid = threadIdx.x;
    const int w = tid >> 6, l = tid & 63;
    const int l16 = l & 15, lg = l >> 4;
    const int phys = blockIdx.x;        // 512 blocks
    const int logi = (phys & 7) * 64 + (phys >> 3);   // XCD-contiguous (512%8==0)
    const int qt6 = logi & 15;          // q-tile (128 rows each)
    const int pair = logi >> 4;         // 0..31
    const int h = pair & 7, bi = pair >> 3;
    const int qw = qt6 * 128 + w * 32;
    const int swz = (l16 & 7) << 2;     // u32-index swizzle for P
    uint* sPw = &sPu[w][0];

    const ushort* Kb = qt + (size_t)bi * N_TOK * 1024 + 512 + h * 64;  // [kv][1024]
    const ushort* Vb = vc + (size_t)(bi * 512 + h * 64) * N_TOK;       // [d][2048]

    // Q fragments (B-operand): lane: col=l16 -> q = qw + Mt*16 + l16, k=lg*8+j
    short8 qf[2][2];
    #pragma unroll
    for (int Mt = 0; Mt < 2; Mt++)
        #pragma unroll
        for (int kt = 0; kt < 2; kt++)
            qf[Mt][kt] = *(const short8*)(qt +
                ((size_t)(bi * N_TOK + qw + Mt * 16 + l16) * 1024 + h * 64 + kt * 32 + lg * 8));

    f32x4 oacc[2][4];
    #pragma unroll
    for (int Mt = 0; Mt < 2; Mt++)
        #pragma unroll
        for (int dt = 0; dt < 4; dt++) oacc[Mt][dt] = (f32x4){0.f, 0.f, 0.f, 0.f};
    float lsum[2] = {0.f, 0.f};

    for (int t = 0; t < N_TOK / 64; t++) {
        const int kv0 = t * 64;

        // ---- K fragments direct from global (16 rows x 64B per load) ----
        short8 kf[4][2];
        #pragma unroll
        for (int nt = 0; nt < 4; nt++)
            #pragma unroll
            for (int kt = 0; kt < 2; kt++)
                kf[nt][kt] = *(const short8*)(Kb +
                    (size_t)(kv0 + nt * 16 + l16) * 1024 + kt * 32 + lg * 8);

        // ---- S^T = K Q : lane holds q=Mt*16+l16, kv = nt*16 + lg*4 + r ----
        f32x4 sacc[2][4];
        #pragma unroll
        for (int Mt = 0; Mt < 2; Mt++)
            #pragma unroll
            for (int nt = 0; nt < 4; nt++) sacc[Mt][nt] = (f32x4){0.f, 0.f, 0.f, 0.f};
        __builtin_amdgcn_s_setprio(1);
        #pragma unroll
        for (int nt = 0; nt < 4; nt++)
            #pragma unroll
            for (int kt = 0; kt < 2; kt++)
                #pragma unroll
                for (int Mt = 0; Mt < 2; Mt++)
                    sacc[Mt][nt] = __builtin_amdgcn_mfma_f32_16x16x32_bf16(
                        kf[nt][kt], qf[Mt][kt], sacc[Mt][nt], 0, 0, 0);
        __builtin_amdgcn_s_setprio(0);

        // ---- softmax numerator: p = 2^s; pack -> per-wave LDS ----
        #pragma unroll
        for (int Mt = 0; Mt < 2; Mt++) {
            float ps = 0.f;
            #pragma unroll
            for (int nt = 0; nt < 4; nt++)
                #pragma unroll
                for (int r = 0; r < 4; r++) {
                    float p = __builtin_amdgcn_exp2f(sacc[Mt][nt][r]);
                    sacc[Mt][nt][r] = p;
                    ps += p;
                }
            ps += __shfl_xor(ps, 16);
            ps += __shfl_xor(ps, 32);
            lsum[Mt] += ps;
            #pragma unroll
            for (int nt = 0; nt < 4; nt++) {
                float a0 = sacc[Mt][nt][0], a1 = sacc[Mt][nt][1];
                float a2 = sacc[Mt][nt][2], a3 = sacc[Mt][nt][3];
                uint u0, u1;
                asm("v_cvt_pk_bf16_f32 %0, %1, %2" : "=v"(u0) : "v"(a0), "v"(a1));
                asm("v_cvt_pk_bf16_f32 %0, %1, %2" : "=v"(u1) : "v"(a2), "v"(a3));
                int col = ((nt * 4 + lg) * 2) ^ swz;
                *(uint2*)&sPw[Mt * 512 + l16 * 32 + col] = make_uint2(u0, u1);
            }
        }

        // ---- O += P V : V fragments direct from global, reused across Mt ----
        #pragma unroll
        for (int kt = 0; kt < 2; kt++) {
            short8 pf[2];
            #pragma unroll
            for (int Mt = 0; Mt < 2; Mt++)
                pf[Mt] = *(const short8*)&sPw[Mt * 512 + l16 * 32 +
                                              ((kt * 16 + lg * 4) ^ swz)];
            __builtin_amdgcn_s_setprio(1);
            #pragma unroll
            for (int dt = 0; dt < 4; dt++) {
                short8 vf = *(const short8*)(Vb +
                    (size_t)(dt * 16 + l16) * N_TOK + kv0 + kt * 32 + lg * 8);
                #pragma unroll
                for (int Mt = 0; Mt < 2; Mt++)
                    oacc[Mt][dt] = __builtin_amdgcn_mfma_f32_16x16x32_bf16(
                        pf[Mt], vf, oacc[Mt][dt], 0, 0, 0);
            }
            __builtin_amdgcn_s_setprio(0);
        }
    }

    // ---- epilogue: normalize -> bf16 token-major ----
    #pragma unroll
    for (int Mt = 0; Mt < 2; Mt++) {
        float rl = 1.f / lsum[Mt];
        float rr[4];
        #pragma unroll
        for (int r = 0; r < 4; r++) rr[r] = __shfl(rl, lg * 4 + r);
        #pragma unroll
        for (int dt = 0; dt < 4; dt++) {
            int ch = h * 64 + dt * 16 + l16;
            #pragma unroll
            for (int r = 0; r < 4; r++) {
                int tok = qw + Mt * 16 + lg * 4 + r;
                aout[((size_t)bi * N_TOK + tok) * 512 + ch] = f2bf(oacc[Mt][dt][r] * rr[r]);
            }
        }
    }
}

extern "C" void kernel_launch(void* const* d_in, const int* in_sizes, int n_in,
                              void* d_out, int out_size, void* d_ws, size_t ws_size,
                              hipStream_t stream) {
    const float* x    = (const float*)d_in[0];
    const float* Wqkv = (const float*)d_in[1];
    const float* Wout = (const float*)d_in[2];
    const float* bout = (const float*)d_in[3];
    const float* g1   = (const float*)d_in[4];
    const float* be1  = (const float*)d_in[5];
    const float* m1   = (const float*)d_in[6];
    const float* v1   = (const float*)d_in[7];
    const float* Wffn = (const float*)d_in[8];
    const float* g2   = (const float*)d_in[9];
    const float* be2  = (const float*)d_in[10];
    const float* m2   = (const float*)d_in[11];
    const float* v2   = (const float*)d_in[12];

    char* ws = (char*)d_ws;
    ushort* wqB  = (ushort*)(ws + 0);          // 1.5 MB
    ushort* woB  = (ushort*)(ws + 1572864);    // 0.5 MB
    ushort* wfB  = (ushort*)(ws + 2097152);    // 0.5 MB
    ushort* xt   = (ushort*)(ws + 2621440);    // 8 MB   [b][2048][512] bf16
    ushort* qtp  = (ushort*)(ws + 11010048);   // 16 MB  [b][2048][1024] bf16
    ushort* vcp  = (ushort*)(ws + 27787264);   // 8 MB   [b][512][2048] bf16
    ushort* aout = (ushort*)(ws + 36175872);   // 8 MB   [b][2048][512] bf16
    ushort* attB = (ushort*)(ws + 27787264);   // 8 MB   reuse vcp region (dead after attn)

    dim3 blk(256);
    prep<<<2304, blk, 0, stream>>>(Wqkv, wqB, Wout, woB, Wffn, wfB, x, xt);
    bgemm<0, 128, 128><<<dim3(16, 12, 4), blk, 0, stream>>>(
        wqB, xt, 1536, qtp, vcp, nullptr, nullptr,
        nullptr, nullptr, nullptr, nullptr, nullptr, nullptr);
    attn_mfma<<<dim3(512), blk, 0, stream>>>(qtp, vcp, aout);
    bgemm<1, 64, 128><<<dim3(16, 8, 4), blk, 0, stream>>>(
        woB, aout, 512, nullptr, nullptr, nullptr, attB,
        bout, g1, be1, m1, v1, xt);
    bgemm<2, 64, 128><<<dim3(16, 8, 4), blk, 0, stream>>>(
        wfB, attB, 512, nullptr, nullptr, (float*)d_out, nullptr,
        nullptr, g2, be2, m2, v2, attB);
}

// Round 10
// 126.479 us; speedup vs baseline: 1.4285x; 1.4285x over previous
//
#include <hip/hip_runtime.h>
#include <math.h>

#define N_TOK 2048

typedef __attribute__((ext_vector_type(8))) short short8;   // 8 bf16
typedef __attribute__((ext_vector_type(4))) float f32x4;

__device__ __forceinline__ float gelu_f(float v) {
    return 0.5f * v * (1.0f + erff(v * 0.7071067811865475f));
}
__device__ __forceinline__ ushort f2bf(float x) {
    uint u = __float_as_uint(x);
    uint r = u + 0x7FFFu + ((u >> 16) & 1u);
    return (ushort)(r >> 16);
}
__device__ __forceinline__ float bf2f(ushort u) {
    return __uint_as_float((uint)u << 16);
}
// async global->LDS, 16B per lane; LDS dest = wave-uniform base + lane*16
__device__ __forceinline__ void gload16(const void* g, void* s) {
    __builtin_amdgcn_global_load_lds((const __attribute__((address_space(1))) void*)g,
                                     (__attribute__((address_space(3))) void*)s, 16, 0, 0);
}

// ---- prep: weight f32->bf16 convert (blocks 0..1279) + x transpose (1280..2303) ----
__global__ __launch_bounds__(256)
void prep(const float* __restrict__ w0, ushort* __restrict__ o0,
          const float* __restrict__ w1, ushort* __restrict__ o1,
          const float* __restrict__ w2, ushort* __restrict__ o2,
          const float* __restrict__ x, ushort* __restrict__ xt)
{
    __shared__ ushort sT[64 * 68];
    const int tid = threadIdx.x;
    int bx = blockIdx.x;
    if (bx < 1280) {
        int i4 = bx * 256 + tid;   // 327680 float4s total
        const float* src; ushort* dst; int idx;
        if (i4 < 196608)      { src = w0; dst = o0; idx = i4; }
        else if (i4 < 262144) { src = w1; dst = o1; idx = i4 - 196608; }
        else                  { src = w2; dst = o2; idx = i4 - 262144; }
        float4 v = *(const float4*)&src[idx * 4];
        ushort4 p; p.x = f2bf(v.x); p.y = f2bf(v.y); p.z = f2bf(v.z); p.w = f2bf(v.w);
        *(ushort4*)&dst[idx * 4] = p;
        return;
    }
    bx -= 1280;                                 // 1024 transpose blocks
    const int tok0 = (bx & 31) * 64;
    const int ch0 = ((bx >> 5) & 7) * 64;
    const int bi = bx >> 8;
    #pragma unroll
    for (int i = 0; i < 4; i++) {
        int ch = (tid >> 4) + i * 16;
        int t4 = (tid & 15) * 4;
        float4 v = *(const float4*)&x[((size_t)bi * 512 + ch0 + ch) * N_TOK + tok0 + t4];
        ushort4 p; p.x = f2bf(v.x); p.y = f2bf(v.y); p.z = f2bf(v.z); p.w = f2bf(v.w);
        *(ushort4*)&sT[ch * 68 + t4] = p;
    }
    __syncthreads();
    const int tr = (tid & 15) + (tid >> 6) * 16;
    const int cb = ((tid >> 4) & 3) * 16;
    uint vv[8];
    #pragma unroll
    for (int j = 0; j < 8; j++) {
        uint lo = sT[(cb + 2 * j) * 68 + tr];
        uint hi = sT[(cb + 2 * j + 1) * 68 + tr];
        vv[j] = lo | (hi << 16);
    }
    size_t base = ((size_t)bi * N_TOK + tok0 + tr) * 512 + ch0 + cb;
    *(uint4*)&xt[base]     = *(uint4*)&vv[0];
    *(uint4*)&xt[base + 8] = *(uint4*)&vv[4];
}

// ---- bf16 MFMA GEMM: C[b] = A @ Bt[b]^T (structure unchanged) ----
template<int MODE, int BM, int BN>
__global__ __launch_bounds__(256)
void bgemm(const ushort* __restrict__ A, const ushort* __restrict__ Bt, int M,
           ushort* __restrict__ qt, ushort* __restrict__ vc,
           float* __restrict__ outF, ushort* __restrict__ outB,
           const float* __restrict__ bias,
           const float* __restrict__ g, const float* __restrict__ be,
           const float* __restrict__ mu, const float* __restrict__ va,
           const ushort* __restrict__ residB)
{
    constexpr int MF = BM / 32, NF = BN / 32;
    __shared__ ushort sA[BM * 64];
    __shared__ ushort sB[BN * 64];
    const int tid = threadIdx.x;
    const int w = tid >> 6, l = tid & 63;
    const int l16 = l & 15, lg = l >> 4;
    const int wr = w >> 1, wc = w & 1;
    const int bi = blockIdx.z;
    const int m0 = blockIdx.y * BM, n0 = blockIdx.x * BN;
    const ushort* Bb = Bt + (size_t)bi * N_TOK * 512;
    const int srow = l >> 3, spos = l & 7;

    f32x4 acc[MF][NF];
    #pragma unroll
    for (int i = 0; i < MF; i++)
        #pragma unroll
        for (int j = 0; j < NF; j++) acc[i][j] = (f32x4){0.f, 0.f, 0.f, 0.f};

    for (int kt = 0; kt < 512; kt += 64) {
        __syncthreads();
        #pragma unroll
        for (int i = 0; i < BM / 32; i++) {
            int row = w * (BM / 4) + i * 8 + srow;
            int c = spos ^ (row & 7);
            gload16(A + (size_t)(m0 + row) * 512 + kt + c * 8,
                    sA + (w * (BM / 4) + i * 8) * 64);
        }
        #pragma unroll
        for (int i = 0; i < BN / 32; i++) {
            int row = w * (BN / 4) + i * 8 + srow;
            int c = spos ^ (row & 7);
            gload16(Bb + (size_t)(n0 + row) * 512 + kt + c * 8,
                    sB + (w * (BN / 4) + i * 8) * 64);
        }
        __syncthreads();
        #pragma unroll
        for (int ks = 0; ks < 2; ks++) {
            short8 af[MF], bfv[NF];
            #pragma unroll
            for (int mi = 0; mi < MF; mi++) {
                int row = wr * (BM / 2) + mi * 16 + l16;
                af[mi] = *(const short8*)&sA[row * 64 + (((ks * 4 + lg) ^ (row & 7)) << 3)];
            }
            #pragma unroll
            for (int ni = 0; ni < NF; ni++) {
                int row = wc * (BN / 2) + ni * 16 + l16;
                bfv[ni] = *(const short8*)&sB[row * 64 + (((ks * 4 + lg) ^ (row & 7)) << 3)];
            }
            __builtin_amdgcn_s_setprio(1);
            #pragma unroll
            for (int mi = 0; mi < MF; mi++)
                #pragma unroll
                for (int ni = 0; ni < NF; ni++)
                    acc[mi][ni] = __builtin_amdgcn_mfma_f32_16x16x32_bf16(
                        af[mi], bfv[ni], acc[mi][ni], 0, 0, 0);
            __builtin_amdgcn_s_setprio(0);
        }
    }

    const int chb = m0 + wr * (BM / 2);
    const int tkb = n0 + wc * (BN / 2);
    if (MODE == 0) {
        if (m0 < 1024) {
            // Q gets 0.125 * log2(e) so attention can use exp2 directly
            const float qs = (m0 < 512) ? 0.18033688f : 1.0f;
            #pragma unroll
            for (int mi = 0; mi < MF; mi++) {
                int ob = chb + mi * 16 + lg * 4;
                #pragma unroll
                for (int ni = 0; ni < NF; ni++) {
                    int tok = tkb + ni * 16 + l16;
                    ushort4 p;
                    p.x = f2bf(acc[mi][ni][0] * qs); p.y = f2bf(acc[mi][ni][1] * qs);
                    p.z = f2bf(acc[mi][ni][2] * qs); p.w = f2bf(acc[mi][ni][3] * qs);
                    *(ushort4*)&qt[((size_t)bi * N_TOK + tok) * 1024 + ob] = p;
                }
            }
        } else {
            #pragma unroll
            for (int mi = 0; mi < MF; mi++)
                #pragma unroll
                for (int r = 0; r < 4; r++) {
                    int o = chb + mi * 16 + lg * 4 + r - 1024;
                    #pragma unroll
                    for (int ni = 0; ni < NF; ni++) {
                        int tok = tkb + ni * 16 + l16;
                        vc[((size_t)bi * 512 + o) * N_TOK + tok] = f2bf(acc[mi][ni][r]);
                    }
                }
        }
    } else {
        #pragma unroll
        for (int mi = 0; mi < MF; mi++) {
            float inv[4], sh[4], bb[4];
            #pragma unroll
            for (int r = 0; r < 4; r++) {
                int o = chb + mi * 16 + lg * 4 + r;
                inv[r] = g[o] * rsqrtf(va[o] + 1e-5f);
                sh[r]  = be[o] - mu[o] * inv[r];
                bb[r]  = (MODE == 1) ? bias[o] : 0.f;
            }
            #pragma unroll
            for (int ni = 0; ni < NF; ni++) {
                int tok = tkb + ni * 16 + l16;
                ushort4 rv = *(const ushort4*)&residB[((size_t)bi * N_TOK + tok) * 512 +
                                                      chb + mi * 16 + lg * 4];
                float rr_[4] = {bf2f(rv.x), bf2f(rv.y), bf2f(rv.z), bf2f(rv.w)};
                float ov[4];
                #pragma unroll
                for (int r = 0; r < 4; r++) {
                    float y = (acc[mi][ni][r] + bb[r]) * inv[r] + sh[r];
                    ov[r] = gelu_f((MODE == 1) ? (y + rr_[r]) : (rr_[r] + y));
                }
                if (MODE == 1) {
                    ushort4 p;
                    p.x = f2bf(ov[0]); p.y = f2bf(ov[1]);
                    p.z = f2bf(ov[2]); p.w = f2bf(ov[3]);
                    *(ushort4*)&outB[((size_t)bi * N_TOK + tok) * 512 +
                                     chb + mi * 16 + lg * 4] = p;
                } else {
                    #pragma unroll
                    for (int r = 0; r < 4; r++) {
                        int o = chb + mi * 16 + lg * 4 + r;
                        outF[((size_t)bi * 512 + o) * N_TOK + tok] = ov[r];
                    }
                }
            }
        }
    }
}

// ---- MFMA flash attention: split-KV, Mt=2, 16 waves/CU ----
// Block = 4 waves: qsub = w&1 (which 32 q-rows), kvh = w>>1 (which 1024-kv half).
// Fixed-max softmax (m=0) => partial (O, l) over kv halves merge by ADDITION.
// Grid 1024 blocks (XCD-clustered), LDS 80KB -> 2 blocks/CU = 16 waves/CU.
// qt: bf16 [b][2048][1024] (Q pre-scaled by 0.125*log2e, K ch 512..1023)
// vc: bf16 [b][512][2048]; aout: bf16 [b][2048][512]
__global__ __launch_bounds__(256)
void attn_mfma(const ushort* __restrict__ qt, const ushort* __restrict__ vc,
               ushort* __restrict__ aout)
{
    __shared__ ushort sK[2][2][64 * 64];   // [kvh][buf][tok][d]  32KB
    __shared__ ushort sV[2][2][64 * 64];   // [kvh][buf][d][kv]   32KB
    __shared__ uint   sPu[4][1024];        // per-wave P (loop) / O-merge (epilogue) 16KB
    const int tid = threadIdx.x;
    const int w = tid >> 6, l = tid & 63;
    const int l16 = l & 15, lg = l >> 4;
    const int qsub = w & 1, kvh = w >> 1;
    const int phys = blockIdx.x;           // 1024 blocks
    const int logi = (phys & 7) * 128 + (phys >> 3);   // XCD-contiguous
    const int qblk = logi & 31;            // 32 q-blocks of 64 rows per (bi,h)
    const int pair = logi >> 5;
    const int h = pair & 7, bi = pair >> 3;
    const int qw = qblk * 64 + qsub * 32;
    const int srow = l >> 3, spos = l & 7;
    const int swz = (l16 & 7) << 2;        // u32-index swizzle for P
    uint* sPw = &sPu[w][0];
    ushort* sKh = &sK[kvh][0][0];
    ushort* sVh = &sV[kvh][0][0];
    const int kvbase = kvh * 1024;         // this half's token offset

    const ushort* kSrc = qt + (size_t)bi * N_TOK * 1024 + 512 + h * 64 + ((spos ^ srow) << 3);
    const ushort* vSrc = vc + (size_t)(bi * 512 + h * 64) * N_TOK + ((spos ^ srow) << 3);

    // Q fragments (B-operand): lane: col=l16 -> q = qw + Mt*16 + l16, k=lg*8+j
    short8 qf[2][2];
    #pragma unroll
    for (int Mt = 0; Mt < 2; Mt++)
        #pragma unroll
        for (int kt = 0; kt < 2; kt++)
            qf[Mt][kt] = *(const short8*)(qt +
                ((size_t)(bi * N_TOK + qw + Mt * 16 + l16) * 1024 + h * 64 + kt * 32 + lg * 8));

    f32x4 oacc[2][4];
    #pragma unroll
    for (int Mt = 0; Mt < 2; Mt++)
        #pragma unroll
        for (int dt = 0; dt < 4; dt++) oacc[Mt][dt] = (f32x4){0.f, 0.f, 0.f, 0.f};
    float lsum[2] = {0.f, 0.f};

    // prologue: the 2 waves of each kv-half stage tile 0 of that half into buf 0
    #pragma unroll
    for (int i = 0; i < 4; i++) {
        int rb = i * 16 + qsub * 8;
        gload16(kSrc + (size_t)(kvbase + rb + srow) * 1024, &sKh[rb * 64]);
        gload16(vSrc + (size_t)(rb + srow) * N_TOK + kvbase, &sVh[rb * 64]);
    }

    for (int t = 0; t < 16; t++) {
        const int cur = t & 1;
        __syncthreads();   // buf[cur] ready (vmcnt drained); prev reads of buf[cur^1] done
        if (t + 1 < 16) {
            const int kv1 = kvbase + (t + 1) * 64;
            #pragma unroll
            for (int i = 0; i < 4; i++) {
                int rb = i * 16 + qsub * 8;
                gload16(kSrc + (size_t)(kv1 + rb + srow) * 1024,
                        &sKh[(cur ^ 1) * 4096 + rb * 64]);
                gload16(vSrc + (size_t)(rb + srow) * N_TOK + kv1,
                        &sVh[(cur ^ 1) * 4096 + rb * 64]);
            }
        }

        // ---- S^T = K Q : lane holds q=Mt*16+l16, kv = nt*16 + lg*4 + r ----
        f32x4 sacc[2][4];
        #pragma unroll
        for (int Mt = 0; Mt < 2; Mt++)
            #pragma unroll
            for (int nt = 0; nt < 4; nt++) sacc[Mt][nt] = (f32x4){0.f, 0.f, 0.f, 0.f};
        __builtin_amdgcn_s_setprio(1);
        #pragma unroll
        for (int nt = 0; nt < 4; nt++)
            #pragma unroll
            for (int kt = 0; kt < 2; kt++) {
                short8 kf = *(const short8*)&sKh[cur * 4096 + (nt * 16 + l16) * 64 +
                                                 (((kt * 4 + lg) ^ (l16 & 7)) << 3)];
                #pragma unroll
                for (int Mt = 0; Mt < 2; Mt++)
                    sacc[Mt][nt] = __builtin_amdgcn_mfma_f32_16x16x32_bf16(
                        kf, qf[Mt][kt], sacc[Mt][nt], 0, 0, 0);
            }
        __builtin_amdgcn_s_setprio(0);

        // ---- softmax numerator: p = 2^s; pack -> per-wave LDS ----
        #pragma unroll
        for (int Mt = 0; Mt < 2; Mt++) {
            float ps = 0.f;
            #pragma unroll
            for (int nt = 0; nt < 4; nt++)
                #pragma unroll
                for (int r = 0; r < 4; r++) {
                    float p = __builtin_amdgcn_exp2f(sacc[Mt][nt][r]);
                    sacc[Mt][nt][r] = p;
                    ps += p;
                }
            ps += __shfl_xor(ps, 16);
            ps += __shfl_xor(ps, 32);
            lsum[Mt] += ps;
            #pragma unroll
            for (int nt = 0; nt < 4; nt++) {
                float a0 = sacc[Mt][nt][0], a1 = sacc[Mt][nt][1];
                float a2 = sacc[Mt][nt][2], a3 = sacc[Mt][nt][3];
                uint u0, u1;
                asm("v_cvt_pk_bf16_f32 %0, %1, %2" : "=v"(u0) : "v"(a0), "v"(a1));
                asm("v_cvt_pk_bf16_f32 %0, %1, %2" : "=v"(u1) : "v"(a2), "v"(a3));
                int col = ((nt * 4 + lg) * 2) ^ swz;
                *(uint2*)&sPw[Mt * 512 + l16 * 32 + col] = make_uint2(u0, u1);
            }
        }

        // ---- O += P V : V fragment read once, used by both Mt ----
        #pragma unroll
        for (int kt = 0; kt < 2; kt++) {
            short8 pf[2];
            #pragma unroll
            for (int Mt = 0; Mt < 2; Mt++)
                pf[Mt] = *(const short8*)&sPw[Mt * 512 + l16 * 32 +
                                              ((kt * 16 + lg * 4) ^ swz)];
            __builtin_amdgcn_s_setprio(1);
            #pragma unroll
            for (int dt = 0; dt < 4; dt++) {
                short8 vf = *(const short8*)&sVh[cur * 4096 + (dt * 16 + l16) * 64 +
                                                 (((kt * 4 + lg) ^ (l16 & 7)) << 3)];
                #pragma unroll
                for (int Mt = 0; Mt < 2; Mt++)
                    oacc[Mt][dt] = __builtin_amdgcn_mfma_f32_16x16x32_bf16(
                        pf[Mt], vf, oacc[Mt][dt], 0, 0, 0);
            }
            __builtin_amdgcn_s_setprio(0);
        }
    }

    // ---- merge kv-halves: kvh=1 waves export (O as bf16 pairs, lsum); kvh=0 add ----
    __syncthreads();                       // all P-region reads done; safe to reuse
    uint* ex = &sPu[0][0] + qsub * 1088;   // [17][64] uints per q-subtile
    if (kvh == 1) {
        #pragma unroll
        for (int Mt = 0; Mt < 2; Mt++) {
            #pragma unroll
            for (int dt = 0; dt < 4; dt++) {
                float a0 = oacc[Mt][dt][0], a1 = oacc[Mt][dt][1];
                float a2 = oacc[Mt][dt][2], a3 = oacc[Mt][dt][3];
                uint u0, u1;
                asm("v_cvt_pk_bf16_f32 %0, %1, %2" : "=v"(u0) : "v"(a0), "v"(a1));
                asm("v_cvt_pk_bf16_f32 %0, %1, %2" : "=v"(u1) : "v"(a2), "v"(a3));
                ex[(Mt * 8 + dt * 2 + 0) * 64 + l] = u0;
                ex[(Mt * 8 + dt * 2 + 1) * 64 + l] = u1;
            }
            if (lg == 0) ex[16 * 64 + Mt * 16 + l16] = __float_as_uint(lsum[Mt]);
        }
    }
    __syncthreads();
    if (kvh == 0) {
        #pragma unroll
        for (int Mt = 0; Mt < 2; Mt++) {
            #pragma unroll
            for (int dt = 0; dt < 4; dt++) {
                uint u0 = ex[(Mt * 8 + dt * 2 + 0) * 64 + l];
                uint u1 = ex[(Mt * 8 + dt * 2 + 1) * 64 + l];
                oacc[Mt][dt][0] += bf2f((ushort)(u0 & 0xffff));
                oacc[Mt][dt][1] += bf2f((ushort)(u0 >> 16));
                oacc[Mt][dt][2] += bf2f((ushort)(u1 & 0xffff));
                oacc[Mt][dt][3] += bf2f((ushort)(u1 >> 16));
            }
            lsum[Mt] += __uint_as_float(ex[16 * 64 + Mt * 16 + l16]);
        }
        // ---- normalize -> bf16 token-major ----
        #pragma unroll
        for (int Mt = 0; Mt < 2; Mt++) {
            float rl = 1.f / lsum[Mt];
            float rr[4];
            #pragma unroll
            for (int r = 0; r < 4; r++) rr[r] = __shfl(rl, lg * 4 + r);
            #pragma unroll
            for (int dt = 0; dt < 4; dt++) {
                int ch = h * 64 + dt * 16 + l16;
                #pragma unroll
                for (int r = 0; r < 4; r++) {
                    int tok = qw + Mt * 16 + lg * 4 + r;
                    aout[((size_t)bi * N_TOK + tok) * 512 + ch] =
                        f2bf(oacc[Mt][dt][r] * rr[r]);
                }
            }
        }
    }
}

extern "C" void kernel_launch(void* const* d_in, const int* in_sizes, int n_in,
                              void* d_out, int out_size, void* d_ws, size_t ws_size,
                              hipStream_t stream) {
    const float* x    = (const float*)d_in[0];
    const float* Wqkv = (const float*)d_in[1];
    const float* Wout = (const float*)d_in[2];
    const float* bout = (const float*)d_in[3];
    const float* g1   = (const float*)d_in[4];
    const float* be1  = (const float*)d_in[5];
    const float* m1   = (const float*)d_in[6];
    const float* v1   = (const float*)d_in[7];
    const float* Wffn = (const float*)d_in[8];
    const float* g2   = (const float*)d_in[9];
    const float* be2  = (const float*)d_in[10];
    const float* m2   = (const float*)d_in[11];
    const float* v2   = (const float*)d_in[12];

    char* ws = (char*)d_ws;
    ushort* wqB  = (ushort*)(ws + 0);          // 1.5 MB
    ushort* woB  = (ushort*)(ws + 1572864);    // 0.5 MB
    ushort* wfB  = (ushort*)(ws + 2097152);    // 0.5 MB
    ushort* xt   = (ushort*)(ws + 2621440);    // 8 MB   [b][2048][512] bf16
    ushort* qtp  = (ushort*)(ws + 11010048);   // 16 MB  [b][2048][1024] bf16
    ushort* vcp  = (ushort*)(ws + 27787264);   // 8 MB   [b][512][2048] bf16
    ushort* aout = (ushort*)(ws + 36175872);   // 8 MB   [b][2048][512] bf16
    ushort* attB = (ushort*)(ws + 27787264);   // 8 MB   reuse vcp region (dead after attn)

    dim3 blk(256);
    prep<<<2304, blk, 0, stream>>>(Wqkv, wqB, Wout, woB, Wffn, wfB, x, xt);
    bgemm<0, 128, 128><<<dim3(16, 12, 4), blk, 0, stream>>>(
        wqB, xt, 1536, qtp, vcp, nullptr, nullptr,
        nullptr, nullptr, nullptr, nullptr, nullptr, nullptr);
    attn_mfma<<<dim3(1024), blk, 0, stream>>>(qtp, vcp, aout);
    bgemm<1, 64, 128><<<dim3(16, 8, 4), blk, 0, stream>>>(
        woB, aout, 512, nullptr, nullptr, nullptr, attB,
        bout, g1, be1, m1, v1, xt);
    bgemm<2, 64, 128><<<dim3(16, 8, 4), blk, 0, stream>>>(
        wfB, attB, 512, nullptr, nullptr, (float*)d_out, nullptr,
        nullptr, g2, be2, m2, v2, attB);
}

// Round 11
// 123.007 us; speedup vs baseline: 1.4688x; 1.0282x over previous
//
#include <hip/hip_runtime.h>
#include <math.h>

#define N_TOK 2048

typedef __attribute__((ext_vector_type(8))) short short8;    // 8 bf16
typedef __attribute__((ext_vector_type(4))) float f32x4;
typedef __attribute__((ext_vector_type(16))) float f32x16;

__device__ __forceinline__ float gelu_f(float v) {
    return 0.5f * v * (1.0f + erff(v * 0.7071067811865475f));
}
__device__ __forceinline__ ushort f2bf(float x) {
    uint u = __float_as_uint(x);
    uint r = u + 0x7FFFu + ((u >> 16) & 1u);
    return (ushort)(r >> 16);
}
__device__ __forceinline__ float bf2f(ushort u) {
    return __uint_as_float((uint)u << 16);
}
// async global->LDS, 16B per lane; LDS dest = wave-uniform base + lane*16
__device__ __forceinline__ void gload16(const void* g, void* s) {
    __builtin_amdgcn_global_load_lds((const __attribute__((address_space(1))) void*)g,
                                     (__attribute__((address_space(3))) void*)s, 16, 0, 0);
}

// ---- prep: weight f32->bf16 convert (blocks 0..1279) + x transpose (1280..2303) ----
__global__ __launch_bounds__(256)
void prep(const float* __restrict__ w0, ushort* __restrict__ o0,
          const float* __restrict__ w1, ushort* __restrict__ o1,
          const float* __restrict__ w2, ushort* __restrict__ o2,
          const float* __restrict__ x, ushort* __restrict__ xt)
{
    __shared__ ushort sT[64 * 68];
    const int tid = threadIdx.x;
    int bx = blockIdx.x;
    if (bx < 1280) {
        int i4 = bx * 256 + tid;   // 327680 float4s total
        const float* src; ushort* dst; int idx;
        if (i4 < 196608)      { src = w0; dst = o0; idx = i4; }
        else if (i4 < 262144) { src = w1; dst = o1; idx = i4 - 196608; }
        else                  { src = w2; dst = o2; idx = i4 - 262144; }
        float4 v = *(const float4*)&src[idx * 4];
        ushort4 p; p.x = f2bf(v.x); p.y = f2bf(v.y); p.z = f2bf(v.z); p.w = f2bf(v.w);
        *(ushort4*)&dst[idx * 4] = p;
        return;
    }
    bx -= 1280;                                 // 1024 transpose blocks
    const int tok0 = (bx & 31) * 64;
    const int ch0 = ((bx >> 5) & 7) * 64;
    const int bi = bx >> 8;
    #pragma unroll
    for (int i = 0; i < 4; i++) {
        int ch = (tid >> 4) + i * 16;
        int t4 = (tid & 15) * 4;
        float4 v = *(const float4*)&x[((size_t)bi * 512 + ch0 + ch) * N_TOK + tok0 + t4];
        ushort4 p; p.x = f2bf(v.x); p.y = f2bf(v.y); p.z = f2bf(v.z); p.w = f2bf(v.w);
        *(ushort4*)&sT[ch * 68 + t4] = p;
    }
    __syncthreads();
    const int tr = (tid & 15) + (tid >> 6) * 16;
    const int cb = ((tid >> 4) & 3) * 16;
    uint vv[8];
    #pragma unroll
    for (int j = 0; j < 8; j++) {
        uint lo = sT[(cb + 2 * j) * 68 + tr];
        uint hi = sT[(cb + 2 * j + 1) * 68 + tr];
        vv[j] = lo | (hi << 16);
    }
    size_t base = ((size_t)bi * N_TOK + tok0 + tr) * 512 + ch0 + cb;
    *(uint4*)&xt[base]     = *(uint4*)&vv[0];
    *(uint4*)&xt[base + 8] = *(uint4*)&vv[4];
}

// ---- bf16 MFMA GEMM: C[b] = A @ Bt[b]^T (structure unchanged) ----
template<int MODE, int BM, int BN>
__global__ __launch_bounds__(256)
void bgemm(const ushort* __restrict__ A, const ushort* __restrict__ Bt, int M,
           ushort* __restrict__ qt, ushort* __restrict__ vc,
           float* __restrict__ outF, ushort* __restrict__ outB,
           const float* __restrict__ bias,
           const float* __restrict__ g, const float* __restrict__ be,
           const float* __restrict__ mu, const float* __restrict__ va,
           const ushort* __restrict__ residB)
{
    constexpr int MF = BM / 32, NF = BN / 32;
    __shared__ ushort sA[BM * 64];
    __shared__ ushort sB[BN * 64];
    const int tid = threadIdx.x;
    const int w = tid >> 6, l = tid & 63;
    const int l16 = l & 15, lg = l >> 4;
    const int wr = w >> 1, wc = w & 1;
    const int bi = blockIdx.z;
    const int m0 = blockIdx.y * BM, n0 = blockIdx.x * BN;
    const ushort* Bb = Bt + (size_t)bi * N_TOK * 512;
    const int srow = l >> 3, spos = l & 7;

    f32x4 acc[MF][NF];
    #pragma unroll
    for (int i = 0; i < MF; i++)
        #pragma unroll
        for (int j = 0; j < NF; j++) acc[i][j] = (f32x4){0.f, 0.f, 0.f, 0.f};

    for (int kt = 0; kt < 512; kt += 64) {
        __syncthreads();
        #pragma unroll
        for (int i = 0; i < BM / 32; i++) {
            int row = w * (BM / 4) + i * 8 + srow;
            int c = spos ^ (row & 7);
            gload16(A + (size_t)(m0 + row) * 512 + kt + c * 8,
                    sA + (w * (BM / 4) + i * 8) * 64);
        }
        #pragma unroll
        for (int i = 0; i < BN / 32; i++) {
            int row = w * (BN / 4) + i * 8 + srow;
            int c = spos ^ (row & 7);
            gload16(Bb + (size_t)(n0 + row) * 512 + kt + c * 8,
                    sB + (w * (BN / 4) + i * 8) * 64);
        }
        __syncthreads();
        #pragma unroll
        for (int ks = 0; ks < 2; ks++) {
            short8 af[MF], bfv[NF];
            #pragma unroll
            for (int mi = 0; mi < MF; mi++) {
                int row = wr * (BM / 2) + mi * 16 + l16;
                af[mi] = *(const short8*)&sA[row * 64 + (((ks * 4 + lg) ^ (row & 7)) << 3)];
            }
            #pragma unroll
            for (int ni = 0; ni < NF; ni++) {
                int row = wc * (BN / 2) + ni * 16 + l16;
                bfv[ni] = *(const short8*)&sB[row * 64 + (((ks * 4 + lg) ^ (row & 7)) << 3)];
            }
            __builtin_amdgcn_s_setprio(1);
            #pragma unroll
            for (int mi = 0; mi < MF; mi++)
                #pragma unroll
                for (int ni = 0; ni < NF; ni++)
                    acc[mi][ni] = __builtin_amdgcn_mfma_f32_16x16x32_bf16(
                        af[mi], bfv[ni], acc[mi][ni], 0, 0, 0);
            __builtin_amdgcn_s_setprio(0);
        }
    }

    const int chb = m0 + wr * (BM / 2);
    const int tkb = n0 + wc * (BN / 2);
    if (MODE == 0) {
        if (m0 < 1024) {
            // Q gets 0.125 * log2(e) so attention can use exp2 directly
            const float qs = (m0 < 512) ? 0.18033688f : 1.0f;
            #pragma unroll
            for (int mi = 0; mi < MF; mi++) {
                int ob = chb + mi * 16 + lg * 4;
                #pragma unroll
                for (int ni = 0; ni < NF; ni++) {
                    int tok = tkb + ni * 16 + l16;
                    ushort4 p;
                    p.x = f2bf(acc[mi][ni][0] * qs); p.y = f2bf(acc[mi][ni][1] * qs);
                    p.z = f2bf(acc[mi][ni][2] * qs); p.w = f2bf(acc[mi][ni][3] * qs);
                    *(ushort4*)&qt[((size_t)bi * N_TOK + tok) * 1024 + ob] = p;
                }
            }
        } else {
            #pragma unroll
            for (int mi = 0; mi < MF; mi++)
                #pragma unroll
                for (int r = 0; r < 4; r++) {
                    int o = chb + mi * 16 + lg * 4 + r - 1024;
                    #pragma unroll
                    for (int ni = 0; ni < NF; ni++) {
                        int tok = tkb + ni * 16 + l16;
                        vc[((size_t)bi * 512 + o) * N_TOK + tok] = f2bf(acc[mi][ni][r]);
                    }
                }
        }
    } else {
        #pragma unroll
        for (int mi = 0; mi < MF; mi++) {
            float inv[4], sh[4], bb[4];
            #pragma unroll
            for (int r = 0; r < 4; r++) {
                int o = chb + mi * 16 + lg * 4 + r;
                inv[r] = g[o] * rsqrtf(va[o] + 1e-5f);
                sh[r]  = be[o] - mu[o] * inv[r];
                bb[r]  = (MODE == 1) ? bias[o] : 0.f;
            }
            #pragma unroll
            for (int ni = 0; ni < NF; ni++) {
                int tok = tkb + ni * 16 + l16;
                ushort4 rv = *(const ushort4*)&residB[((size_t)bi * N_TOK + tok) * 512 +
                                                      chb + mi * 16 + lg * 4];
                float rr_[4] = {bf2f(rv.x), bf2f(rv.y), bf2f(rv.z), bf2f(rv.w)};
                float ov[4];
                #pragma unroll
                for (int r = 0; r < 4; r++) {
                    float y = (acc[mi][ni][r] + bb[r]) * inv[r] + sh[r];
                    ov[r] = gelu_f((MODE == 1) ? (y + rr_[r]) : (rr_[r] + y));
                }
                if (MODE == 1) {
                    ushort4 p;
                    p.x = f2bf(ov[0]); p.y = f2bf(ov[1]);
                    p.z = f2bf(ov[2]); p.w = f2bf(ov[3]);
                    *(ushort4*)&outB[((size_t)bi * N_TOK + tok) * 512 +
                                     chb + mi * 16 + lg * 4] = p;
                } else {
                    #pragma unroll
                    for (int r = 0; r < 4; r++) {
                        int o = chb + mi * 16 + lg * 4 + r;
                        outF[((size_t)bi * 512 + o) * N_TOK + tok] = ov[r];
                    }
                }
            }
        }
    }
}

// ---- MFMA flash attention: 32x32 MFMA, fully in-register P via permlane32_swap ----
// qt: bf16 [b][2048][1024] (Q pre-scaled by 0.125*log2e ch 0..511, K ch 512..1023)
// vc: bf16 [b][512][2048]; aout: bf16 [b][2048][512]
// 2 waves/block (32 q each), KV tiles of 64, double-buffered gload16 staging.
// S^T = K·Q (32x32): lane(c,h) holds q=c, kv rows 8g+4h+m. cvt_pk pairs ->
// permlane32_swap builds PV A-frags (kv=16t+8h+j) with ZERO LDS traffic.
// O^T = V^T·P^T: lane holds q=c for all its 32 outputs -> 1/lsum lane-local.
__global__ __launch_bounds__(128)
void attn_mfma(const ushort* __restrict__ qt, const ushort* __restrict__ vc,
               ushort* __restrict__ aout)
{
    __shared__ ushort sK[2][64 * 64];   // [buf][tok][d], linear dest (pre-swz src)
    __shared__ ushort sV[2][64 * 64];   // [buf][d][kv]
    const int tid = threadIdx.x;
    const int w = tid >> 6, l = tid & 63;
    const int c = l & 31, h = l >> 5;
    const int phys = blockIdx.x;                        // 1024 blocks
    const int logi = (phys & 7) * 128 + (phys >> 3);    // XCD-contiguous
    const int qblk = logi & 31;
    const int pair = logi >> 5;
    const int hh = pair & 7, bi = pair >> 3;
    const int qw = qblk * 64 + w * 32;
    const int srow = l >> 3, spos = l & 7;

    const ushort* kSrc = qt + (size_t)bi * N_TOK * 1024 + 512 + hh * 64 + ((spos ^ srow) << 3);
    const ushort* vSrc = vc + (size_t)(bi * 512 + hh * 64) * N_TOK + ((spos ^ srow) << 3);

    // Q (B-operand): lane(c,h): Q[qw+c][d = dk*16 + 8h + j]
    short8 qf[4];
    #pragma unroll
    for (int dk = 0; dk < 4; dk++)
        qf[dk] = *(const short8*)(qt +
            (size_t)(bi * N_TOK + qw + c) * 1024 + hh * 64 + dk * 16 + h * 8);

    f32x16 oacc[2];
    #pragma unroll
    for (int dt = 0; dt < 2; dt++)
        #pragma unroll
        for (int i = 0; i < 16; i++) oacc[dt][i] = 0.f;
    float lsum = 0.f;

    // prologue: stage tile 0 into buf 0 (128 threads, 4 rounds each for K and V)
    #pragma unroll
    for (int i = 0; i < 4; i++) {
        int rb = i * 16 + w * 8;
        gload16(kSrc + (size_t)(rb + srow) * 1024, &sK[0][rb * 64]);
        gload16(vSrc + (size_t)(rb + srow) * N_TOK, &sV[0][rb * 64]);
    }

    for (int t = 0; t < N_TOK / 64; t++) {
        const int cur = t & 1;
        __syncthreads();   // buf[cur] ready (barrier drains vmcnt); prev reads done
        if (t + 1 < N_TOK / 64) {
            const int kv1 = (t + 1) * 64;
            #pragma unroll
            for (int i = 0; i < 4; i++) {
                int rb = i * 16 + w * 8;
                gload16(kSrc + (size_t)(kv1 + rb + srow) * 1024,
                        &sK[cur ^ 1][rb * 64]);
                gload16(vSrc + (size_t)(rb + srow) * N_TOK + kv1,
                        &sV[cur ^ 1][rb * 64]);
            }
        }

        #pragma unroll
        for (int s = 0; s < 2; s++) {          // two 32-kv subtiles per staged 64
            // ---- S^T = K Q : A=K (row=kv, k=d), B=Q (col=q, k=d) ----
            f32x16 sacc;
            #pragma unroll
            for (int i = 0; i < 16; i++) sacc[i] = 0.f;
            __builtin_amdgcn_s_setprio(1);
            #pragma unroll
            for (int dk = 0; dk < 4; dk++) {
                int row = s * 32 + c;
                short8 kf = *(const short8*)&sK[cur][row * 64 +
                             (((dk * 2 + h) ^ (row & 7)) << 3)];
                sacc = __builtin_amdgcn_mfma_f32_32x32x16_bf16(kf, qf[dk], sacc, 0, 0, 0);
            }
            __builtin_amdgcn_s_setprio(0);

            // ---- p = 2^s (m=0 safe: |s|max ~1.2); pack to bf16 pairs in-reg ----
            uint u0_0, u0_1, u1_0, u1_1, u2_0, u2_1, u3_0, u3_1;
            float ps = 0.f;
            {
                float p0, p1, p2, p3;
#define PACK_G(G, U0, U1) \
                p0 = __builtin_amdgcn_exp2f(sacc[4*G+0]); \
                p1 = __builtin_amdgcn_exp2f(sacc[4*G+1]); \
                p2 = __builtin_amdgcn_exp2f(sacc[4*G+2]); \
                p3 = __builtin_amdgcn_exp2f(sacc[4*G+3]); \
                ps += (p0 + p1) + (p2 + p3); \
                asm("v_cvt_pk_bf16_f32 %0, %1, %2" : "=v"(U0) : "v"(p0), "v"(p1)); \
                asm("v_cvt_pk_bf16_f32 %0, %1, %2" : "=v"(U1) : "v"(p2), "v"(p3));
                PACK_G(0, u0_0, u0_1)
                PACK_G(1, u1_0, u1_1)
                PACK_G(2, u2_0, u2_1)
                PACK_G(3, u3_0, u3_1)
#undef PACK_G
            }
            lsum += ps;

            // ---- PV: A-frag via permlane32_swap (halves exchange), B=V from LDS ----
            // t2=0 uses groups {0,1}; t2=1 uses {2,3}.
#define PV_STEP(T2, A0, A1, B0, B1) \
            { \
                uint a0 = A0, b0 = B0, a1 = A1, b1 = B1; \
                asm volatile("v_permlane32_swap_b32 %0, %1" : "+v"(b0), "+v"(a0)); \
                asm volatile("v_permlane32_swap_b32 %0, %1" : "+v"(b1), "+v"(a1)); \
                uint4 fu = make_uint4(a0, a1, b0, b1); \
                short8 pf = *(short8*)&fu; \
                __builtin_amdgcn_s_setprio(1); \
                _Pragma("unroll") \
                for (int dt = 0; dt < 2; dt++) { \
                    int row = dt * 32 + c; \
                    short8 vf = *(const short8*)&sV[cur][row * 64 + \
                                 (((s * 4 + T2 * 2 + h) ^ (row & 7)) << 3)]; \
                    oacc[dt] = __builtin_amdgcn_mfma_f32_32x32x16_bf16( \
                        pf, vf, oacc[dt], 0, 0, 0); \
                } \
                __builtin_amdgcn_s_setprio(0); \
            }
            PV_STEP(0, u0_0, u0_1, u1_0, u1_1)
            PV_STEP(1, u2_0, u2_1, u3_0, u3_1)
#undef PV_STEP
        }
    }

    // ---- epilogue: q = c for every value this lane holds -> lane-local 1/l ----
    lsum += __shfl_xor(lsum, 32);
    float rl = 1.f / lsum;
    #pragma unroll
    for (int dt = 0; dt < 2; dt++)
        #pragma unroll
        for (int g = 0; g < 4; g++) {
            float o0 = oacc[dt][4 * g + 0] * rl;
            float o1 = oacc[dt][4 * g + 1] * rl;
            float o2 = oacc[dt][4 * g + 2] * rl;
            float o3 = oacc[dt][4 * g + 3] * rl;
            uint p0, p1;
            asm("v_cvt_pk_bf16_f32 %0, %1, %2" : "=v"(p0) : "v"(o0), "v"(o1));
            asm("v_cvt_pk_bf16_f32 %0, %1, %2" : "=v"(p1) : "v"(o2), "v"(o3));
            int ch = hh * 64 + dt * 32 + 8 * g + 4 * h;
            *(uint2*)&aout[((size_t)bi * N_TOK + qw + c) * 512 + ch] = make_uint2(p0, p1);
        }
}

extern "C" void kernel_launch(void* const* d_in, const int* in_sizes, int n_in,
                              void* d_out, int out_size, void* d_ws, size_t ws_size,
                              hipStream_t stream) {
    const float* x    = (const float*)d_in[0];
    const float* Wqkv = (const float*)d_in[1];
    const float* Wout = (const float*)d_in[2];
    const float* bout = (const float*)d_in[3];
    const float* g1   = (const float*)d_in[4];
    const float* be1  = (const float*)d_in[5];
    const float* m1   = (const float*)d_in[6];
    const float* v1   = (const float*)d_in[7];
    const float* Wffn = (const float*)d_in[8];
    const float* g2   = (const float*)d_in[9];
    const float* be2  = (const float*)d_in[10];
    const float* m2   = (const float*)d_in[11];
    const float* v2   = (const float*)d_in[12];

    char* ws = (char*)d_ws;
    ushort* wqB  = (ushort*)(ws + 0);          // 1.5 MB
    ushort* woB  = (ushort*)(ws + 1572864);    // 0.5 MB
    ushort* wfB  = (ushort*)(ws + 2097152);    // 0.5 MB
    ushort* xt   = (ushort*)(ws + 2621440);    // 8 MB   [b][2048][512] bf16
    ushort* qtp  = (ushort*)(ws + 11010048);   // 16 MB  [b][2048][1024] bf16
    ushort* vcp  = (ushort*)(ws + 27787264);   // 8 MB   [b][512][2048] bf16
    ushort* aout = (ushort*)(ws + 36175872);   // 8 MB   [b][2048][512] bf16
    ushort* attB = (ushort*)(ws + 27787264);   // 8 MB   reuse vcp region (dead after attn)

    dim3 blk(256);
    prep<<<2304, blk, 0, stream>>>(Wqkv, wqB, Wout, woB, Wffn, wfB, x, xt);
    bgemm<0, 128, 128><<<dim3(16, 12, 4), blk, 0, stream>>>(
        wqB, xt, 1536, qtp, vcp, nullptr, nullptr,
        nullptr, nullptr, nullptr, nullptr, nullptr, nullptr);
    attn_mfma<<<dim3(1024), dim3(128), 0, stream>>>(qtp, vcp, aout);
    bgemm<1, 64, 128><<<dim3(16, 8, 4), blk, 0, stream>>>(
        woB, aout, 512, nullptr, nullptr, nullptr, attB,
        bout, g1, be1, m1, v1, xt);
    bgemm<2, 64, 128><<<dim3(16, 8, 4), blk, 0, stream>>>(
        wfB, attB, 512, nullptr, nullptr, (float*)d_out, nullptr,
        nullptr, g2, be2, m2, v2, attB);
}